// Round 8
// baseline (280.959 us; speedup 1.0000x reference)
//
#include <hip/hip_runtime.h>

#define H 320
#define W 320
#define HW (H * W)          // 102400
#define CH 64

typedef _Float16 f16;
typedef _Float16 f16x8 __attribute__((ext_vector_type(8)));
typedef float f32x16 __attribute__((ext_vector_type(16)));

// ---------------- bicubic weight (A=-0.75) ----------------------------------
__device__ __forceinline__ float cubw(float t) {
    t = fabsf(t);
    if (t <= 1.f) return (1.25f * t - 2.25f) * t * t + 1.f;
    if (t < 2.f)  return -0.75f * (((t - 5.f) * t + 8.f) * t - 4.f);
    return 0.f;
}

// bicubic x2 sample of one query channel at output pixel (gy,gx), gy,gx in [0,320)
__device__ __forceinline__ float bicub(const float* __restrict__ qc, int gy, int gx) {
    float sy = gy * 0.5f - 0.25f;
    float sx = gx * 0.5f - 0.25f;
    int iy0 = (int)floorf(sy), ix0 = (int)floorf(sx);
    float o = 0.f;
#pragma unroll
    for (int b = 0; b < 4; b++) {
        int tx = ix0 - 1 + b;
        float wxv = cubw(sx - (float)tx);
        int txc = min(max(tx, 0), 159);
        float s = 0.f;
#pragma unroll
        for (int a = 0; a < 4; a++) {
            int ty = iy0 - 1 + a;
            float wyv = cubw(sy - (float)ty);
            int tyc = min(max(ty, 0), 159);
            s += wyv * qc[tyc * 160 + txc];
        }
        o += wxv * s;
    }
    return o;
}

// ---------------- conv1 (fused bicubic + MFMA) + mconv weight repack --------
// R8: one launch, 843 blocks. Blocks 0..799: conv1 (batch0 = query via inline
// bicubic, batch1 = ref), with conv1's 5 B-fragments built inline per lane
// from conv1_w (bit-identical to the old wr5 path). Blocks 800..842: repack
// the 5 mconv layers' weights into wrep (consumed by the next launch).
__global__ __launch_bounds__(256) void hconv_m(const float* __restrict__ query,
                                               const float* __restrict__ ref,
                                               const float* __restrict__ conv1_w,
                                               const float* __restrict__ bias,
                                               const float* __restrict__ w0, // r1_w1
                                               const float* __restrict__ w1, // r1_w2
                                               const float* __restrict__ w2, // pr_w1
                                               const float* __restrict__ w3, // pr_w2
                                               const float* __restrict__ w4, // p1_w
                                               f16* __restrict__ wrep,
                                               f16* __restrict__ out) {
    __shared__ float tile[3][12][40];        // rows y0-2..y0+9, cols x0-2..x0+37
    const int tid = threadIdx.x;

    if (blockIdx.x >= 800) {                 // ---- weight repack blocks ----
        int li = (blockIdx.x - 800) * 256 + tid;
        if (li >= 11008) return;
        const float* src;
        int CIN, KS2, base, rel;
        if (li < 1152)       { src = w0; CIN = 32; KS2 = 9;  base = 0;     rel = li; }
        else if (li < 2304)  { src = w1; CIN = 32; KS2 = 9;  base = 9216;  rel = li - 1152; }
        else if (li < 3456)  { src = w2; CIN = 32; KS2 = 9;  base = 18432; rel = li - 2304; }
        else if (li < 4608)  { src = w3; CIN = 32; KS2 = 9;  base = 27648; rel = li - 3456; }
        else                 { src = w4; CIN = 64; KS2 = 25; base = 36864; rel = li - 4608; }
        int fi = rel >> 6, l = rel & 63;
        int kc = fi / KS2, t = fi - kc * KS2;
        int oc = l & 31, kh = l >> 5;
#pragma unroll
        for (int i = 0; i < 8; ++i) {
            int ic = kc * 16 + kh * 8 + i;
            wrep[base + rel * 8 + i] = (f16)src[(oc * CIN + ic) * KS2 + t];
        }
        return;
    }

    const int b = blockIdx.x >= 400 ? 1 : 0;
    const int tb = blockIdx.x - b * 400;
    f16* o = out + (size_t)b * (32 * HW);
    const int x0 = (tb % 10) * 32, y0 = (tb / 10) * 8;

    const int lane = tid & 63, wv = tid >> 6;
    const int R = lane & 31, hh = lane >> 5;

    // inline conv1 B-fragments (K=80 tap-folded: k = tap*3+ic, k>=75 -> 0)
    f16x8 bw[5];
#pragma unroll
    for (int kc = 0; kc < 5; ++kc)
#pragma unroll
        for (int i = 0; i < 8; ++i) {
            int k = kc * 16 + hh * 8 + i;
            f16 v = (f16)0.f;
            if (k < 75) {
                int tap = k / 3, ic = k - 3 * tap;      // tap = ky*5+kx
                v = (f16)conv1_w[(R * 3 + ic) * 25 + tap];
            }
            bw[kc][i] = v;
        }

    for (int idx = tid; idx < 1440; idx += 256) {
        int ic = idx / 480;
        int rem = idx - ic * 480;
        int r = rem / 40, c = rem - r * 40;
        int gy = y0 - 2 + r, gx = x0 - 2 + c;
        float v = 0.f;
        if (gy >= 0 && gy < H && gx >= 0 && gx < W)
            v = b ? ref[ic * HW + gy * W + gx]
                  : bicub(query + ic * 25600, gy, gx);
        tile[ic][r][c] = v;
    }
    __syncthreads();

    f32x16 acc0, acc1;
#pragma unroll
    for (int j = 0; j < 16; ++j) { acc0[j] = 0.f; acc1[j] = 0.f; }

#pragma unroll
    for (int kc = 0; kc < 5; ++kc) {
#pragma unroll
        for (int m = 0; m < 2; ++m) {
            f16x8 A;
#pragma unroll
            for (int i = 0; i < 8; ++i) {
                int k = kc * 16 + hh * 8 + i;
                float v = 0.f;
                if (k < 75) {
                    int tap = k / 3, ic = k - 3 * tap;
                    int dy = tap / 5, dx = tap - 5 * dy;
                    v = tile[ic][2 * wv + m + dy][R + dx];
                }
                A[i] = (f16)v;
            }
            if (m == 0) acc0 = __builtin_amdgcn_mfma_f32_32x32x16_f16(A, bw[kc], acc0, 0, 0, 0);
            else        acc1 = __builtin_amdgcn_mfma_f32_32x32x16_f16(A, bw[kc], acc1, 0, 0, 0);
        }
    }

    const float bv = bias[R];
#pragma unroll
    for (int m = 0; m < 2; ++m) {
        const int gy = y0 + 2 * wv + m;
        f32x16 a = m ? acc1 : acc0;
#pragma unroll
        for (int r = 0; r < 16; ++r) {
            int X = x0 + (r & 3) + 8 * (r >> 2) + 4 * hh;
            float v = a[r] + bv;
            v = (v > 0.f) ? v : 0.2f * v;              // lrelu
            o[(gy * W + X) * 32 + R] = (f16)v;
        }
    }
}

// ---------------- MFMA implicit-GEMM conv (NHWC f16 in/out, fp32 accum) -----
// Tap-decomposed GEMM on v_mfma_f32_32x32x16_f16 (verified R2). R2W = rows
// per wave (1 = 4-row tile, 8 blocks/CU for 3x3; now also used for 5x5 to
// double latency hiding: LDS 36.9 KB, grid 800). AFF: fuse the 1x1 affine
// conv into the epilogue — for fixed acc reg r, the 32-lane half-wave holds
// one pixel's 32 channels (D col = oc, row = pixel), so a 5-step shfl_xor
// reduce + lane-0 write yields affine for that pixel.
template <int KS, int CIN, int ACT, bool RES, int R2W, bool AFF>
__global__ __launch_bounds__(256) void mconv_k(const f16* __restrict__ in,
                                               const f16* __restrict__ wrep,
                                               const float* __restrict__ bias,
                                               const f16* __restrict__ res,
                                               f16* __restrict__ out,
                                               int OUTC, int inStr, int resStr,
                                               int outStr, int oc0Base, int oc0Step,
                                               const float* __restrict__ aw,
                                               const float* __restrict__ ab,
                                               float* __restrict__ affout) {
    constexpr int PAD = KS / 2;
    constexpr int TROWS = 4 * R2W;
    constexpr int TY = TROWS + 2 * PAD;
    constexpr int TX = 32 + 2 * PAD;
    constexpr int NPX = TY * TX;
    constexpr int NU = CIN / 4;           // 8B units per pixel
    constexpr int UM = NU - 1;
    constexpr int KC = CIN / 16;
    constexpr int KS2 = KS * KS;
    constexpr int BPB = 800 / R2W;        // blocks per batch image

    __shared__ uint2 lds2[NPX * NU];

    const int b = blockIdx.x >= BPB ? 1 : 0;
    const int tb = blockIdx.x - b * BPB;
    in  += (size_t)b * inStr;
    res += (size_t)b * resStr;
    out += (size_t)b * outStr;
    const int oc0 = oc0Base + b * oc0Step;

    const int tid = threadIdx.x;
    const int bx = tb % 10;
    const int by = tb / 10;
    const int x0 = bx * 32, y0 = by * TROWS;

    // ---- stage NHWC tile (+halo), coalesced 8B loads, swizzled ds_writes ---
    {
        const int cu = tid & UM;
        constexpr int STEP = 256 / NU;
        for (int p = tid / NU; p < NPX; p += STEP) {
            int ly = p / TX, lx = p - ly * TX;
            int gy = y0 - PAD + ly, gx = x0 - PAD + lx;
            uint2 v; v.x = 0u; v.y = 0u;
            if (gy >= 0 && gy < H && gx >= 0 && gx < W)
                v = *reinterpret_cast<const uint2*>(in + (gy * W + gx) * CIN + cu * 4);
            lds2[p * NU + (cu ^ (p & UM))] = v;
        }
    }
    __syncthreads();

    const int lane = tid & 63;
    const int wv = tid >> 6;              // wave 0..3
    const int R = lane & 31;              // A pixel-x / B,D oc column
    const int hh = lane >> 5;

    f32x16 acc0, acc1;
#pragma unroll
    for (int j = 0; j < 16; ++j) { acc0[j] = 0.f; acc1[j] = 0.f; }

#pragma unroll
    for (int kc = 0; kc < KC; ++kc) {
#pragma unroll
        for (int t = 0; t < KS2; ++t) {
            const int dy = t / KS, dx = t - dy * KS;
            f16x8 B = *reinterpret_cast<const f16x8*>(
                wrep + ((kc * KS2 + t) * 64 + lane) * 8);
            const int u0 = (kc * 2 + hh) * 2;
            {   // m = 0
                int p = (R2W * wv + 0 + dy) * TX + R + dx;
                union { uint2 u[2]; f16x8 v; } A;
                A.u[0] = lds2[p * NU + ((u0)     ^ (p & UM))];
                A.u[1] = lds2[p * NU + ((u0 + 1) ^ (p & UM))];
                acc0 = __builtin_amdgcn_mfma_f32_32x32x16_f16(A.v, B, acc0, 0, 0, 0);
            }
            if constexpr (R2W == 2) {   // m = 1
                int p = (R2W * wv + 1 + dy) * TX + R + dx;
                union { uint2 u[2]; f16x8 v; } A;
                A.u[0] = lds2[p * NU + ((u0)     ^ (p & UM))];
                A.u[1] = lds2[p * NU + ((u0 + 1) ^ (p & UM))];
                acc1 = __builtin_amdgcn_mfma_f32_32x32x16_f16(A.v, B, acc1, 0, 0, 0);
            }
        }
    }

    // ---- epilogue: bias (+res) + activation, NHWC f16 stores (+affine) -----
    const float bv = bias[R];
#pragma unroll
    for (int m = 0; m < R2W; ++m) {
        const int gy = y0 + R2W * wv + m;
        f32x16 a = m ? acc1 : acc0;
#pragma unroll
        for (int r = 0; r < 16; ++r) {
            int X = x0 + (r & 3) + 8 * (r >> 2) + 4 * hh;
            int pix = gy * W + X;
            float v = a[r] + bv;
            if constexpr (RES) v += (float)res[pix * 32 + R];
            if constexpr (ACT == 0) v = fmaxf(v, 0.f);
            else                    v = (v > 0.f) ? v : 0.2f * v;
            f16 vq = (f16)v;
            out[pix * OUTC + oc0 + R] = vq;
            if constexpr (AFF) {
                float vh = (float)vq;     // post-quant value, as affine_k saw
                float s0 = vh * aw[R];
                float s1 = vh * aw[32 + R];
                float s2 = vh * aw[64 + R];
#pragma unroll
                for (int msk = 16; msk >= 1; msk >>= 1) {
                    s0 += __shfl_xor(s0, msk);
                    s1 += __shfl_xor(s1, msk);
                    s2 += __shfl_xor(s2, msk);
                }
                if (R == 0) {
                    affout[pix]          = fminf(fmaxf(s0 + ab[0] + 1.f, -3.f), 3.f);
                    affout[HW + pix]     = fminf(fmaxf(s1 + ab[1] + 1.f, -3.f), 3.f);
                    affout[2 * HW + pix] = fminf(fmaxf(s2 + ab[2] + 1.f, -3.f), 3.f);
                }
            }
        }
    }
}

// ---------------- deformable 2x2 bilinear sampling --------------------------
// R7 structure kept (near floor): 8-channel groups, LDS 15.4 KB -> 8 blocks/CU,
// grid 12800, cg == XCD via swizzle, row stride 80 (bank-benign), NT stores.
__device__ __forceinline__ int reflmap(int q) {
    int s = q - 1;
    if (s < 0) s = -s;
    else if (s > 319) s = 638 - s;
    return s;
}

__global__ __launch_bounds__(256) void sample_k(const float* __restrict__ x,
                                                const float* __restrict__ aff,
                                                float* __restrict__ outp) {
    __shared__ float tile[8 * 6 * 80];           // 15.4 KB
    int bid = blockIdx.x;                        // 12800 = 8 cg x 1600 tiles
    bid = (bid & 7) * 1600 + (bid >> 3);         // XCD-contiguous: cg == XCD
    const int cg = bid / 1600;                   // 8-channel group
    const int tb = bid - cg * 1600;
    const int h = tb / 5;                        // input row (0..319)
    const int q = tb - 5 * h;                    // 128-col quarter (0..4)
    const int tid = threadIdx.x;
    const int ow = q * 128 + (tid & 127);
    const int oh = 2 * h + (tid >> 7);

    const int w = ow >> 1;
    const int ky = ow & 1, kx = oh & 1;
    const int p = h * W + w;
    float s_x = aff[p];
    float s_y = aff[HW + p];
    float th = (aff[2 * HW + p] - 1.f) * 1.0472f;
    float pnx = kx ? 0.5f : -0.5f;
    float pny = ky ? 0.5f : -0.5f;
    float px = pnx * s_x, py = pny * s_y;
    float st, ct;
    __sincosf(th, &st, &ct);
    float rx = px * ct - py * st;
    float ry = px * st + py * ct;
    float p_x = rx + 0.5f + (float)(h + 1);
    float p_y = ry + 0.5f + (float)(w + 1);
    float ltx = floorf(p_x), lty = floorf(p_y);
    float rbx = ltx + 1.f, rby = lty + 1.f;
    float ltxc = fminf(fmaxf(ltx, 0.f), 321.f);
    float ltyc = fminf(fmaxf(lty, 0.f), 321.f);
    float rbxc = fminf(fmaxf(rbx, 0.f), 321.f);
    float rbyc = fminf(fmaxf(rby, 0.f), 321.f);
    p_x = fminf(fmaxf(p_x, 0.f), 321.f);
    p_y = fminf(fmaxf(p_y, 0.f), 321.f);
    float gx0 = 1.f + ltxc - p_x;
    float gx1 = 1.f - (rbxc - p_x);
    float gy0 = 1.f + ltyc - p_y;
    float gy1 = 1.f - (rbyc - p_y);
    float g_lt = gx0 * gy0, g_rb = gx1 * gy1, g_lb = gx0 * gy1, g_rt = gx1 * gy0;
    int ix0 = reflmap((int)ltxc), ix1 = reflmap((int)rbxc);
    int iy0 = reflmap((int)ltyc), iy1 = reflmap((int)rbyc);

    // LDS word offsets within the staged [6][80-padded] window (in-range
    // proof: ix in [h-2, h+3], iy-colbase in [2, 70]).
    const int rowbase = h - 2;
    const int colbase = q * 64 - 4;
    const int o00 = (ix0 - rowbase) * 80 + (iy0 - colbase);
    const int o01 = (ix0 - rowbase) * 80 + (iy1 - colbase);
    const int o10 = (ix1 - rowbase) * 80 + (iy0 - colbase);
    const int o11 = (ix1 - rowbase) * 80 + (iy1 - colbase);
    const int obase = oh * 640 + ow;
    const int ch0 = cg * 8;

    // stage 8 ch x 6 rows x 18 float4 (72 valid words/row), zero-guarded
    for (int idx = tid; idx < 864; idx += 256) {
        int ch = idx / 108;
        int rem = idx - ch * 108;
        int row = rem / 18;
        int g = rem - row * 18;
        int rv = rowbase + row;
        int cv = colbase + 4 * g;                // 4-aligned
        float4 v = make_float4(0.f, 0.f, 0.f, 0.f);
        if (rv >= 0 && rv < H && cv >= 0 && cv < W)
            v = *reinterpret_cast<const float4*>(x + (size_t)(ch0 + ch) * HW + rv * W + cv);
        *reinterpret_cast<float4*>(&tile[ch * 480 + row * 80 + 4 * g]) = v;
    }
    __syncthreads();

#pragma unroll
    for (int c = 0; c < 8; ++c) {
        const float* t = tile + c * 480;
        float v = g_lt * t[o00] + g_rb * t[o11] + g_lb * t[o01] + g_rt * t[o10];
        __builtin_nontemporal_store(v, outp + (size_t)(ch0 + c) * (640 * 640) + obase);
    }
}

// ---------------- launch ----------------------------------------------------
extern "C" void kernel_launch(void* const* d_in, const int* in_sizes, int n_in,
                              void* d_out, int out_size, void* d_ws, size_t ws_size,
                              hipStream_t stream) {
    const float* x       = (const float*)d_in[0];
    const float* query   = (const float*)d_in[1];
    const float* ref     = (const float*)d_in[2];
    const float* conv1_w = (const float*)d_in[3];
    const float* conv1_b = (const float*)d_in[4];
    const float* r1_w1   = (const float*)d_in[5];
    const float* r1_b1   = (const float*)d_in[6];
    const float* r1_w2   = (const float*)d_in[7];
    const float* r1_b2   = (const float*)d_in[8];
    const float* p1_w    = (const float*)d_in[9];
    const float* p1_b    = (const float*)d_in[10];
    const float* pr_w1   = (const float*)d_in[11];
    const float* pr_b1   = (const float*)d_in[12];
    const float* pr_w2   = (const float*)d_in[13];
    const float* pr_b2   = (const float*)d_in[14];
    const float* p2_w    = (const float*)d_in[15];
    const float* p2_b    = (const float*)d_in[16];

    float* outp = (float*)d_out;
    float* ws = (float*)d_ws;

    // ws (2.4 MB): fp32 affine. d_out (104.8 MB) holds NHWC-f16
    // intermediates + repacked weights; all dead before sample_k rewrites it.
    float* affine = ws;                        // 3*HW fp32
    f16* feat = (f16*)outp;                    // [HW][64] (rf ch 0..31, qf 32..63)
    f16* Bt   = (f16*)(outp + 32 * HW);        // [2][HW][32] batch: 0=q, 1=ref
    f16* Ct   = (f16*)(outp + 64 * HW);        // [2][HW][32]
    f16* Dt   = (f16*)(outp + 96 * HW);        // [HW][32]
    f16* wrep = (f16*)(outp + 112 * HW);       // 88064 f16 repacked mconv weights

    // conv1 (both batches, fused bicubic) + mconv weight repack, one launch
    hconv_m<<<843, 256, 0, stream>>>(query, ref, conv1_w, conv1_b,
                                     r1_w1, r1_w2, pr_w1, pr_w2, p1_w, wrep, Bt);

    // feature-head resblock, batch-2 (batch0 = qf, batch1 = rf)
    mconv_k<3, 32, 0, false, 1, false><<<1600, 256, 0, stream>>>(
        Bt, wrep,        r1_b1, nullptr, Ct, 32, 32 * HW, 0, 32 * HW, 0, 0,
        nullptr, nullptr, nullptr);
    mconv_k<3, 32, 1, true , 1, false><<<1600, 256, 0, stream>>>(
        Ct, wrep + 9216, r1_b2, Bt, feat, 64, 32 * HW, 32 * HW, 0, 32, -32,
        nullptr, nullptr, nullptr);

    // fusion head (single batch); last layer fuses the 1x1 affine conv
    mconv_k<5, 64, 1, false, 1, false><<<800, 256, 0, stream>>>(
        feat, wrep + 36864, p1_b, nullptr, Bt, 32, 0, 0, 0, 0, 0,
        nullptr, nullptr, nullptr);
    mconv_k<3, 32, 0, false, 1, false><<<800, 256, 0, stream>>>(
        Bt, wrep + 18432, pr_b1, nullptr, Ct, 32, 0, 0, 0, 0, 0,
        nullptr, nullptr, nullptr);
    mconv_k<3, 32, 1, true , 1, true ><<<800, 256, 0, stream>>>(
        Ct, wrep + 27648, pr_b2, Bt, Dt, 32, 0, 0, 0, 0, 0,
        p2_w, p2_b, affine);

    sample_k<<<12800, 256, 0, stream>>>(x, affine, outp);
}

// Round 10
// 275.712 us; speedup vs baseline: 1.0190x; 1.0190x over previous
//
#include <hip/hip_runtime.h>

#define H 320
#define W 320
#define HW (H * W)          // 102400
#define CH 64

typedef _Float16 f16;
typedef _Float16 f16x8 __attribute__((ext_vector_type(8)));
typedef float f32x16 __attribute__((ext_vector_type(16)));

// ---------------- bicubic weight (A=-0.75) ----------------------------------
__device__ __forceinline__ float cubw(float t) {
    t = fabsf(t);
    if (t <= 1.f) return (1.25f * t - 2.25f) * t * t + 1.f;
    if (t < 2.f)  return -0.75f * (((t - 5.f) * t + 8.f) * t - 4.f);
    return 0.f;
}

// ---------------- conv1 (fused separable bicubic + MFMA) + weight repack ----
// R10: R9's separable bicubic + the boundary fix — tile halo pixels outside
// the 320x320 image must be ZERO (conv zero-padding); R9 wrote clamp-extended
// bicubic values there (absmax 3.67). Vertical pass now guards on gy/gx.
__global__ __launch_bounds__(256) void hconv_m(const float* __restrict__ query,
                                               const float* __restrict__ ref,
                                               const float* __restrict__ conv1_w,
                                               const float* __restrict__ bias,
                                               const float* __restrict__ w0, // r1_w1
                                               const float* __restrict__ w1, // r1_w2
                                               const float* __restrict__ w2, // pr_w1
                                               const float* __restrict__ w3, // pr_w2
                                               const float* __restrict__ w4, // p1_w
                                               f16* __restrict__ wrep,
                                               f16* __restrict__ out) {
    __shared__ float tile[3][12][40];        // rows y0-2..y0+9, cols x0-2..x0+37
    __shared__ float hbuf[3][10][40];        // horizontal-pass rows rbase..rbase+9
    __shared__ float wxt[40][4];
    __shared__ int   txt[40][4];
    __shared__ float wyt[12][4];
    __shared__ int   tyb[12];
    const int tid = threadIdx.x;

    if (blockIdx.x >= 800) {                 // ---- weight repack blocks ----
        int li = (blockIdx.x - 800) * 256 + tid;
        if (li >= 11008) return;
        const float* src;
        int CIN, KS2, base, rel;
        if (li < 1152)       { src = w0; CIN = 32; KS2 = 9;  base = 0;     rel = li; }
        else if (li < 2304)  { src = w1; CIN = 32; KS2 = 9;  base = 9216;  rel = li - 1152; }
        else if (li < 3456)  { src = w2; CIN = 32; KS2 = 9;  base = 18432; rel = li - 2304; }
        else if (li < 4608)  { src = w3; CIN = 32; KS2 = 9;  base = 27648; rel = li - 3456; }
        else                 { src = w4; CIN = 64; KS2 = 25; base = 36864; rel = li - 4608; }
        int fi = rel >> 6, l = rel & 63;
        int kc = fi / KS2, t = fi - kc * KS2;
        int oc = l & 31, kh = l >> 5;
#pragma unroll
        for (int i = 0; i < 8; ++i) {
            int ic = kc * 16 + kh * 8 + i;
            wrep[base + rel * 8 + i] = (f16)src[(oc * CIN + ic) * KS2 + t];
        }
        return;
    }

    const int b = blockIdx.x >= 400 ? 1 : 0;
    const int tb = blockIdx.x - b * 400;
    f16* o = out + (size_t)b * (32 * HW);
    const int x0 = (tb % 10) * 32, y0 = (tb / 10) * 8;

    const int lane = tid & 63, wv = tid >> 6;
    const int R = lane & 31, hh = lane >> 5;

    // inline conv1 B-fragments (K=80 tap-folded: k = tap*3+ic, k>=75 -> 0)
    f16x8 bw[5];
#pragma unroll
    for (int kc = 0; kc < 5; ++kc)
#pragma unroll
        for (int i = 0; i < 8; ++i) {
            int k = kc * 16 + hh * 8 + i;
            f16 v = (f16)0.f;
            if (k < 75) {
                int tap = k / 3, ic = k - 3 * tap;      // tap = ky*5+kx
                v = (f16)conv1_w[(R * 3 + ic) * 25 + tap];
            }
            bw[kc][i] = v;
        }

    if (b) {                                 // ---- ref: direct stage ----
        for (int idx = tid; idx < 1440; idx += 256) {
            int ic = idx / 480;
            int rem = idx - ic * 480;
            int r = rem / 40, c = rem - r * 40;
            int gy = y0 - 2 + r, gx = x0 - 2 + c;
            float v = 0.f;
            if (gy >= 0 && gy < H && gx >= 0 && gx < W)
                v = ref[ic * HW + gy * W + gx];
            tile[ic][r][c] = v;
        }
        __syncthreads();
    } else {                                 // ---- query: separable bicubic --
        const int rbase = y0 / 2 - 3;        // hbuf source-row base
        if (tid < 40) {                      // wx / tap-col tables (per gx)
            int gx = x0 - 2 + tid;
            float sx = gx * 0.5f - 0.25f;
            int ix0 = (int)floorf(sx);
#pragma unroll
            for (int a = 0; a < 4; ++a) {
                int tx = ix0 - 1 + a;
                wxt[tid][a] = cubw(sx - (float)tx);
                txt[tid][a] = min(max(tx, 0), 159);
            }
        } else if (tid < 52) {               // wy / tap-row base (per gy)
            int r = tid - 40;
            int gy = y0 - 2 + r;
            float sy = gy * 0.5f - 0.25f;
            int iy0 = (int)floorf(sy);
            tyb[r] = iy0 - 1 - rbase;        // hbuf index of tap a=0 (in [0,6])
#pragma unroll
            for (int a = 0; a < 4; ++a)
                wyt[r][a] = cubw(sy - (float)(iy0 - 1 + a));
        }
        __syncthreads();
        // horizontal pass: 3 ic x 10 source rows x 40 out cols
        for (int idx = tid; idx < 1200; idx += 256) {
            int ic = idx / 400;
            int rem = idx - ic * 400;
            int r = rem / 40, c = rem - r * 40;
            int qr = min(max(rbase + r, 0), 159);
            const float* qrow = query + ic * 25600 + qr * 160;
            hbuf[ic][r][c] = wxt[c][0] * qrow[txt[c][0]]
                           + wxt[c][1] * qrow[txt[c][1]]
                           + wxt[c][2] * qrow[txt[c][2]]
                           + wxt[c][3] * qrow[txt[c][3]];
        }
        __syncthreads();
        // vertical pass into tile — ZERO outside the 320x320 image (conv pad)
        for (int idx = tid; idx < 1440; idx += 256) {
            int ic = idx / 480;
            int rem = idx - ic * 480;
            int r = rem / 40, c = rem - r * 40;
            int gy = y0 - 2 + r, gx = x0 - 2 + c;
            float v = 0.f;
            if (gy >= 0 && gy < H && gx >= 0 && gx < W) {
                int tb0 = tyb[r];
                v = wyt[r][0] * hbuf[ic][tb0][c]
                  + wyt[r][1] * hbuf[ic][tb0 + 1][c]
                  + wyt[r][2] * hbuf[ic][tb0 + 2][c]
                  + wyt[r][3] * hbuf[ic][tb0 + 3][c];
            }
            tile[ic][r][c] = v;
        }
        __syncthreads();
    }

    f32x16 acc0, acc1;
#pragma unroll
    for (int j = 0; j < 16; ++j) { acc0[j] = 0.f; acc1[j] = 0.f; }

#pragma unroll
    for (int kc = 0; kc < 5; ++kc) {
#pragma unroll
        for (int m = 0; m < 2; ++m) {
            f16x8 A;
#pragma unroll
            for (int i = 0; i < 8; ++i) {
                int k = kc * 16 + hh * 8 + i;
                float v = 0.f;
                if (k < 75) {
                    int tap = k / 3, ic = k - 3 * tap;
                    int dy = tap / 5, dx = tap - 5 * dy;
                    v = tile[ic][2 * wv + m + dy][R + dx];
                }
                A[i] = (f16)v;
            }
            if (m == 0) acc0 = __builtin_amdgcn_mfma_f32_32x32x16_f16(A, bw[kc], acc0, 0, 0, 0);
            else        acc1 = __builtin_amdgcn_mfma_f32_32x32x16_f16(A, bw[kc], acc1, 0, 0, 0);
        }
    }

    const float bv = bias[R];
#pragma unroll
    for (int m = 0; m < 2; ++m) {
        const int gy = y0 + 2 * wv + m;
        f32x16 a = m ? acc1 : acc0;
#pragma unroll
        for (int r = 0; r < 16; ++r) {
            int X = x0 + (r & 3) + 8 * (r >> 2) + 4 * hh;
            float v = a[r] + bv;
            v = (v > 0.f) ? v : 0.2f * v;              // lrelu
            o[(gy * W + X) * 32 + R] = (f16)v;
        }
    }
}

// ---------------- MFMA implicit-GEMM conv (NHWC f16 in/out, fp32 accum) -----
// Tap-decomposed GEMM on v_mfma_f32_32x32x16_f16 (verified R2). R2W = rows
// per wave: 2 for the 5x5/64ch layer (R8 showed R2W=1 doubles B-fragment L2
// traffic and halo fraction there: +regression), 1 for the 3x3 layers.
template <int KS, int CIN, int ACT, bool RES, int R2W>
__global__ __launch_bounds__(256) void mconv_k(const f16* __restrict__ in,
                                               const f16* __restrict__ wrep,
                                               const float* __restrict__ bias,
                                               const f16* __restrict__ res,
                                               f16* __restrict__ out,
                                               int OUTC, int inStr, int resStr,
                                               int outStr, int oc0Base, int oc0Step) {
    constexpr int PAD = KS / 2;
    constexpr int TROWS = 4 * R2W;
    constexpr int TY = TROWS + 2 * PAD;
    constexpr int TX = 32 + 2 * PAD;
    constexpr int NPX = TY * TX;
    constexpr int NU = CIN / 4;           // 8B units per pixel
    constexpr int UM = NU - 1;
    constexpr int KC = CIN / 16;
    constexpr int KS2 = KS * KS;
    constexpr int BPB = 800 / R2W;        // blocks per batch image

    __shared__ uint2 lds2[NPX * NU];

    const int b = blockIdx.x >= BPB ? 1 : 0;
    const int tb = blockIdx.x - b * BPB;
    in  += (size_t)b * inStr;
    res += (size_t)b * resStr;
    out += (size_t)b * outStr;
    const int oc0 = oc0Base + b * oc0Step;

    const int tid = threadIdx.x;
    const int bx = tb % 10;
    const int by = tb / 10;
    const int x0 = bx * 32, y0 = by * TROWS;

    // ---- stage NHWC tile (+halo), coalesced 8B loads, swizzled ds_writes ---
    {
        const int cu = tid & UM;
        constexpr int STEP = 256 / NU;
        for (int p = tid / NU; p < NPX; p += STEP) {
            int ly = p / TX, lx = p - ly * TX;
            int gy = y0 - PAD + ly, gx = x0 - PAD + lx;
            uint2 v; v.x = 0u; v.y = 0u;
            if (gy >= 0 && gy < H && gx >= 0 && gx < W)
                v = *reinterpret_cast<const uint2*>(in + (gy * W + gx) * CIN + cu * 4);
            lds2[p * NU + (cu ^ (p & UM))] = v;
        }
    }
    __syncthreads();

    const int lane = tid & 63;
    const int wv = tid >> 6;              // wave 0..3
    const int R = lane & 31;              // A pixel-x / B,D oc column
    const int hh = lane >> 5;

    f32x16 acc0, acc1;
#pragma unroll
    for (int j = 0; j < 16; ++j) { acc0[j] = 0.f; acc1[j] = 0.f; }

#pragma unroll
    for (int kc = 0; kc < KC; ++kc) {
#pragma unroll
        for (int t = 0; t < KS2; ++t) {
            const int dy = t / KS, dx = t - dy * KS;
            f16x8 B = *reinterpret_cast<const f16x8*>(
                wrep + ((kc * KS2 + t) * 64 + lane) * 8);
            const int u0 = (kc * 2 + hh) * 2;
            {   // m = 0
                int p = (R2W * wv + 0 + dy) * TX + R + dx;
                union { uint2 u[2]; f16x8 v; } A;
                A.u[0] = lds2[p * NU + ((u0)     ^ (p & UM))];
                A.u[1] = lds2[p * NU + ((u0 + 1) ^ (p & UM))];
                acc0 = __builtin_amdgcn_mfma_f32_32x32x16_f16(A.v, B, acc0, 0, 0, 0);
            }
            if constexpr (R2W == 2) {   // m = 1
                int p = (R2W * wv + 1 + dy) * TX + R + dx;
                union { uint2 u[2]; f16x8 v; } A;
                A.u[0] = lds2[p * NU + ((u0)     ^ (p & UM))];
                A.u[1] = lds2[p * NU + ((u0 + 1) ^ (p & UM))];
                acc1 = __builtin_amdgcn_mfma_f32_32x32x16_f16(A.v, B, acc1, 0, 0, 0);
            }
        }
    }

    // ---- epilogue: bias (+res) + activation, NHWC f16 stores ---------------
    const float bv = bias[R];
#pragma unroll
    for (int m = 0; m < R2W; ++m) {
        const int gy = y0 + R2W * wv + m;
        f32x16 a = m ? acc1 : acc0;
#pragma unroll
        for (int r = 0; r < 16; ++r) {
            int X = x0 + (r & 3) + 8 * (r >> 2) + 4 * hh;
            int pix = gy * W + X;
            float v = a[r] + bv;
            if constexpr (RES) v += (float)res[pix * 32 + R];
            if constexpr (ACT == 0) v = fmaxf(v, 0.f);
            else                    v = (v > 0.f) ? v : 0.2f * v;
            out[pix * OUTC + oc0 + R] = (f16)v;
        }
    }
}

// ---------------- 1x1 conv 32->3 (NHWC f16 in), +1, clip --------------------
__global__ __launch_bounds__(256) void affine_k(const f16* __restrict__ hid,
                                                const float* __restrict__ w,
                                                const float* __restrict__ b,
                                                float* __restrict__ outp) {
    int p = blockIdx.x * 256 + threadIdx.x;
    if (p >= HW) return;
    const f16x8* hv = reinterpret_cast<const f16x8*>(hid + p * 32);
    float a0 = 0.f, a1 = 0.f, a2 = 0.f;
#pragma unroll
    for (int cc = 0; cc < 4; ++cc) {
        f16x8 hb = hv[cc];
#pragma unroll
        for (int j = 0; j < 8; ++j) {
            float hval = (float)hb[j];
            int c = cc * 8 + j;
            a0 += hval * w[c];
            a1 += hval * w[32 + c];
            a2 += hval * w[64 + c];
        }
    }
    a0 = fminf(fmaxf(a0 + b[0] + 1.f, -3.f), 3.f);
    a1 = fminf(fmaxf(a1 + b[1] + 1.f, -3.f), 3.f);
    a2 = fminf(fmaxf(a2 + b[2] + 1.f, -3.f), 3.f);
    outp[p] = a0;
    outp[HW + p] = a1;
    outp[2 * HW + p] = a2;
}

// ---------------- deformable 2x2 bilinear sampling --------------------------
// R7 structure kept (near floor): 8-channel groups, LDS 15.4 KB -> 8 blocks/CU,
// grid 12800, cg == XCD via swizzle, row stride 80 (bank-benign), NT stores.
__device__ __forceinline__ int reflmap(int q) {
    int s = q - 1;
    if (s < 0) s = -s;
    else if (s > 319) s = 638 - s;
    return s;
}

__global__ __launch_bounds__(256) void sample_k(const float* __restrict__ x,
                                                const float* __restrict__ aff,
                                                float* __restrict__ outp) {
    __shared__ float tile[8 * 6 * 80];           // 15.4 KB
    int bid = blockIdx.x;                        // 12800 = 8 cg x 1600 tiles
    bid = (bid & 7) * 1600 + (bid >> 3);         // XCD-contiguous: cg == XCD
    const int cg = bid / 1600;                   // 8-channel group
    const int tb = bid - cg * 1600;
    const int h = tb / 5;                        // input row (0..319)
    const int q = tb - 5 * h;                    // 128-col quarter (0..4)
    const int tid = threadIdx.x;
    const int ow = q * 128 + (tid & 127);
    const int oh = 2 * h + (tid >> 7);

    const int w = ow >> 1;
    const int ky = ow & 1, kx = oh & 1;
    const int p = h * W + w;
    float s_x = aff[p];
    float s_y = aff[HW + p];
    float th = (aff[2 * HW + p] - 1.f) * 1.0472f;
    float pnx = kx ? 0.5f : -0.5f;
    float pny = ky ? 0.5f : -0.5f;
    float px = pnx * s_x, py = pny * s_y;
    float st, ct;
    __sincosf(th, &st, &ct);
    float rx = px * ct - py * st;
    float ry = px * st + py * ct;
    float p_x = rx + 0.5f + (float)(h + 1);
    float p_y = ry + 0.5f + (float)(w + 1);
    float ltx = floorf(p_x), lty = floorf(p_y);
    float rbx = ltx + 1.f, rby = lty + 1.f;
    float ltxc = fminf(fmaxf(ltx, 0.f), 321.f);
    float ltyc = fminf(fmaxf(lty, 0.f), 321.f);
    float rbxc = fminf(fmaxf(rbx, 0.f), 321.f);
    float rbyc = fminf(fmaxf(rby, 0.f), 321.f);
    p_x = fminf(fmaxf(p_x, 0.f), 321.f);
    p_y = fminf(fmaxf(p_y, 0.f), 321.f);
    float gx0 = 1.f + ltxc - p_x;
    float gx1 = 1.f - (rbxc - p_x);
    float gy0 = 1.f + ltyc - p_y;
    float gy1 = 1.f - (rbyc - p_y);
    float g_lt = gx0 * gy0, g_rb = gx1 * gy1, g_lb = gx0 * gy1, g_rt = gx1 * gy0;
    int ix0 = reflmap((int)ltxc), ix1 = reflmap((int)rbxc);
    int iy0 = reflmap((int)ltyc), iy1 = reflmap((int)rbyc);

    // LDS word offsets within the staged [6][80-padded] window (in-range
    // proof: ix in [h-2, h+3], iy-colbase in [2, 70]).
    const int rowbase = h - 2;
    const int colbase = q * 64 - 4;
    const int o00 = (ix0 - rowbase) * 80 + (iy0 - colbase);
    const int o01 = (ix0 - rowbase) * 80 + (iy1 - colbase);
    const int o10 = (ix1 - rowbase) * 80 + (iy0 - colbase);
    const int o11 = (ix1 - rowbase) * 80 + (iy1 - colbase);
    const int obase = oh * 640 + ow;
    const int ch0 = cg * 8;

    // stage 8 ch x 6 rows x 18 float4 (72 valid words/row), zero-guarded
    for (int idx = tid; idx < 864; idx += 256) {
        int ch = idx / 108;
        int rem = idx - ch * 108;
        int row = rem / 18;
        int g = rem - row * 18;
        int rv = rowbase + row;
        int cv = colbase + 4 * g;                // 4-aligned
        float4 v = make_float4(0.f, 0.f, 0.f, 0.f);
        if (rv >= 0 && rv < H && cv >= 0 && cv < W)
            v = *reinterpret_cast<const float4*>(x + (size_t)(ch0 + ch) * HW + rv * W + cv);
        *reinterpret_cast<float4*>(&tile[ch * 480 + row * 80 + 4 * g]) = v;
    }
    __syncthreads();

#pragma unroll
    for (int c = 0; c < 8; ++c) {
        const float* t = tile + c * 480;
        float v = g_lt * t[o00] + g_rb * t[o11] + g_lb * t[o01] + g_rt * t[o10];
        __builtin_nontemporal_store(v, outp + (size_t)(ch0 + c) * (640 * 640) + obase);
    }
}

// ---------------- launch ----------------------------------------------------
extern "C" void kernel_launch(void* const* d_in, const int* in_sizes, int n_in,
                              void* d_out, int out_size, void* d_ws, size_t ws_size,
                              hipStream_t stream) {
    const float* x       = (const float*)d_in[0];
    const float* query   = (const float*)d_in[1];
    const float* ref     = (const float*)d_in[2];
    const float* conv1_w = (const float*)d_in[3];
    const float* conv1_b = (const float*)d_in[4];
    const float* r1_w1   = (const float*)d_in[5];
    const float* r1_b1   = (const float*)d_in[6];
    const float* r1_w2   = (const float*)d_in[7];
    const float* r1_b2   = (const float*)d_in[8];
    const float* p1_w    = (const float*)d_in[9];
    const float* p1_b    = (const float*)d_in[10];
    const float* pr_w1   = (const float*)d_in[11];
    const float* pr_b1   = (const float*)d_in[12];
    const float* pr_w2   = (const float*)d_in[13];
    const float* pr_b2   = (const float*)d_in[14];
    const float* p2_w    = (const float*)d_in[15];
    const float* p2_b    = (const float*)d_in[16];

    float* outp = (float*)d_out;
    float* ws = (float*)d_ws;

    // ws (2.4 MB): fp32 affine. d_out (104.8 MB) holds NHWC-f16
    // intermediates + repacked weights; all dead before sample_k rewrites it.
    float* affine = ws;                        // 3*HW fp32
    f16* feat = (f16*)outp;                    // [HW][64] (rf ch 0..31, qf 32..63)
    f16* Bt   = (f16*)(outp + 32 * HW);        // [2][HW][32] batch: 0=q, 1=ref
    f16* Ct   = (f16*)(outp + 64 * HW);        // [2][HW][32]
    f16* Dt   = (f16*)(outp + 96 * HW);        // [HW][32]
    f16* wrep = (f16*)(outp + 112 * HW);       // 88064 f16 repacked mconv weights

    // conv1 (both batches, fused separable bicubic) + weight repack, one launch
    hconv_m<<<843, 256, 0, stream>>>(query, ref, conv1_w, conv1_b,
                                     r1_w1, r1_w2, pr_w1, pr_w2, p1_w, wrep, Bt);

    // feature-head resblock, batch-2 (batch0 = qf, batch1 = rf)
    mconv_k<3, 32, 0, false, 1><<<1600, 256, 0, stream>>>(
        Bt, wrep,        r1_b1, nullptr, Ct, 32, 32 * HW, 0, 32 * HW, 0, 0);
    mconv_k<3, 32, 1, true , 1><<<1600, 256, 0, stream>>>(
        Ct, wrep + 9216, r1_b2, Bt, feat, 64, 32 * HW, 32 * HW, 0, 32, -32);

    // fusion head (single batch)
    mconv_k<5, 64, 1, false, 2><<<400, 256, 0, stream>>>(
        feat, wrep + 36864, p1_b, nullptr, Bt, 32, 0, 0, 0, 0, 0);
    mconv_k<3, 32, 0, false, 1><<<800, 256, 0, stream>>>(
        Bt, wrep + 18432, pr_b1, nullptr, Ct, 32, 0, 0, 0, 0, 0);
    mconv_k<3, 32, 1, true , 1><<<800, 256, 0, stream>>>(
        Ct, wrep + 27648, pr_b2, Bt, Dt, 32, 0, 0, 0, 0, 0);

    affine_k<<<400, 256, 0, stream>>>(Dt, p2_w, p2_b, affine);

    sample_k<<<12800, 256, 0, stream>>>(x, affine, outp);
}